// Round 1
// baseline (11455.348 us; speedup 1.0000x reference)
//
#include <hip/hip_runtime.h>
#include <cstdint>
#include <cstddef>

#define T_ 256
#define B_ 128
#define E_ 512
#define H_ 1024
#define BH (B_*H_)

typedef _Float16 v8h __attribute__((ext_vector_type(8)));
typedef float    v4f __attribute__((ext_vector_type(4)));

__device__ __forceinline__ float sigmoidf_(float x) {
    return 1.0f / (1.0f + __expf(-x));
}
__device__ __forceinline__ float tanhf_(float x) {
    // tanh(x) = 1 - 2/(exp(2x)+1); saturates correctly at +/-inf
    return 1.0f - 2.0f / (__expf(2.0f * x) + 1.0f);
}

// Register staging set: 1 A-chunk load + 3 B-chunk loads per thread (16B each).
struct Stage { uint4 a, b0, b1, b2; };

// Raw barrier that does NOT drain vmcnt: lets staged global loads stay in
// flight across the barrier (the __syncthreads vmcnt(0) drain was the
// per-chunk latency exposure). lgkmcnt(0) makes our ds_writes visible to the
// other waves before s_barrier; the trailing empty asm pins later LDS reads
// below the barrier.
#define BAR_RELEASE() do { \
    asm volatile("s_waitcnt lgkmcnt(0)" ::: "memory"); \
    __builtin_amdgcn_s_barrier(); \
    asm volatile("" ::: "memory"); \
} while (0)

// Compiler fence: keep the just-issued global loads above the compute phase.
#define PIN() asm volatile("" ::: "memory")

// ---------------------------------------------------------------------------
// Depth-2 software-pipelined GEMM chunk loop.
//   buf0 holds chunk kc, buf1 gets chunk kc+1 (regs loaded 1 iter ago),
//   reg sets receive chunk kc+2/kc+3 (consumed by ds_write next iter).
// One s_barrier per chunk; global loads span ~2 chunks of latency slack.
// ---------------------------------------------------------------------------
__device__ __forceinline__ void gemm_loop(
    int nch, int k0ch,
    _Float16 (&Alds)[2][32][88], _Float16 (&Blds)[2][96][88],
    const _Float16* __restrict__ aseg0, int apitch0,
    const _Float16* __restrict__ aseg1,
    const _Float16* __restrict__ bseg0, int bpitch0,
    const _Float16* __restrict__ bseg1,
    int rtile, int jtile, int tid, v4f* acc)
{
    const int lane = tid & 63, w = tid >> 6;
    const int rh = w & 1, hq = w >> 1;
    const int m = lane & 15, q = lane >> 4;
    const int arow = tid >> 3, ac = tid & 7;

    auto issue = [&](Stage& s, int kc) {
        const bool seg = (kc >= k0ch);
        const int koff = (seg ? (kc - k0ch) : kc) * 64;
        const _Float16* as   = seg ? aseg1 : aseg0;
        const int       ap   = seg ? H_ : apitch0;
        const _Float16* bsrc = seg ? bseg1 : bseg0;
        const int       bp   = seg ? H_ : bpitch0;
        s.a = *(const uint4*)(as + (size_t)(rtile + arow) * ap + koff + ac * 8);
        {
            int id = tid;        int cl = id >> 3, c = id & 7, g = cl >> 5, j = cl & 31;
            s.b0 = *(const uint4*)(bsrc + (size_t)(g * H_ + jtile + j) * bp + koff + c * 8);
        }
        {
            int id = tid + 256;  int cl = id >> 3, c = id & 7, g = cl >> 5, j = cl & 31;
            s.b1 = *(const uint4*)(bsrc + (size_t)(g * H_ + jtile + j) * bp + koff + c * 8);
        }
        {
            int id = tid + 512;  int cl = id >> 3, c = id & 7, g = cl >> 5, j = cl & 31;
            s.b2 = *(const uint4*)(bsrc + (size_t)(g * H_ + jtile + j) * bp + koff + c * 8);
        }
    };

    auto write = [&](const Stage& s, int b) {
        // Compiler inserts the counted s_waitcnt vmcnt(N) here automatically
        // (dependency on the staged regs) — only this set's loads are drained.
        *(uint4*)&Alds[b][arow][ac * 8] = s.a;
        { int id = tid;       *(uint4*)&Blds[b][id >> 3][(id & 7) * 8] = s.b0; }
        { int id = tid + 256; *(uint4*)&Blds[b][id >> 3][(id & 7) * 8] = s.b1; }
        { int id = tid + 512; *(uint4*)&Blds[b][id >> 3][(id & 7) * 8] = s.b2; }
    };

    auto compute = [&](int b, bool seg) {
#pragma unroll
        for (int s = 0; s < 2; ++s) {
            v8h a  = *(const v8h*)&Alds[b][rh * 16 + m][s * 32 + q * 8];
            v8h b0 = *(const v8h*)&Blds[b][ 0 + hq * 16 + m][s * 32 + q * 8];
            v8h b1 = *(const v8h*)&Blds[b][32 + hq * 16 + m][s * 32 + q * 8];
            v8h b2 = *(const v8h*)&Blds[b][64 + hq * 16 + m][s * 32 + q * 8];
            acc[0] = __builtin_amdgcn_mfma_f32_16x16x32_f16(a, b0, acc[0], 0, 0, 0);
            acc[1] = __builtin_amdgcn_mfma_f32_16x16x32_f16(a, b1, acc[1], 0, 0, 0);
            if (seg) acc[3] = __builtin_amdgcn_mfma_f32_16x16x32_f16(a, b2, acc[3], 0, 0, 0);
            else     acc[2] = __builtin_amdgcn_mfma_f32_16x16x32_f16(a, b2, acc[2], 0, 0, 0);
        }
    };

    Stage SA, SB;
    issue(SA, 0);
    issue(SB, 1);
    write(SA, 0);
    BAR_RELEASE();

    // nch is even for both phases (24 / 32) -> chunk kc+1 always valid.
    for (int kc = 0; kc < nch; kc += 2) {
        if (kc + 2 < nch) issue(SA, kc + 2);
        PIN();
        compute(0, kc >= k0ch);
        write(SB, 1);
        BAR_RELEASE();

        if (kc + 3 < nch) issue(SB, kc + 3);
        PIN();
        compute(1, (kc + 1) >= k0ch);
        if (kc + 2 < nch) write(SA, 0);
        BAR_RELEASE();
    }
}

// ---------------------------------------------------------------------------
// Fused per-timestep kernel. Launch k (k=0..T) runs:
//   phase A (blockIdx.z==0): layer0 at t=k      (skipped when k==T)
//   phase B (blockIdx.z==1): layer1 at t=k-1    (skipped when k==0)
// Phase B(k) depends only on phase A(k-1) and phase B(k-1) -> cross-launch
// deps only. fp16 h-shadows and hn0 are ping-ponged on (t&1) to avoid
// intra-launch RAW races (other WGs read full rows of h for the GEMM).
// WG = 32 rows x 32 hidden units (96 gate columns), 4 waves.
// ---------------------------------------------------------------------------
__global__ __launch_bounds__(256) void gru_step(
    const int* __restrict__ bs,
    const _Float16* __restrict__ x16,   // [T][B][E]
    const _Float16* __restrict__ Wi0,   // [3072][512]
    const _Float16* __restrict__ Wh0,   // [3072][1024]
    const _Float16* __restrict__ Wi1,   // [3072][1024]
    const _Float16* __restrict__ Wh1,   // [3072][1024]
    const float* __restrict__ bias,     // [2][4][1024] : br,bz,b_in,b_hn
    float* __restrict__ h0f, float* __restrict__ h1f,      // fp32 masters
    _Float16* __restrict__ h0h, _Float16* __restrict__ h1h, // fp16 shadow x2
    _Float16* __restrict__ hn0,                             // layer0 out x2
    int k)
{
    const int phase = blockIdx.z;
    if (phase == 0 && k >= T_) return;
    if (phase == 1 && k == 0)  return;
    const int t = phase ? (k - 1) : k;
    const int bs_t = bs[t];
    const int rtile = blockIdx.y * 32;
    const int jtile = blockIdx.x * 32;
    const int tid = threadIdx.x;

    const int pr = t & 1, pw = (t + 1) & 1;
    _Float16* hh = phase ? h1h : h0h;
    const _Float16* hh_r = hh + (size_t)pr * BH;
    _Float16*       hh_w = hh + (size_t)pw * BH;

    // Inactive tile: keep the ping-pong coherent by copying the shadow tile.
    if (rtile >= bs_t) {
        if (tid < 128) {
            int r = tid >> 2, c = tid & 3;
            size_t off = (size_t)(rtile + r) * H_ + jtile + c * 8;
            *(uint4*)(hh_w + off) = *(const uint4*)(hh_r + off);
        }
        return;
    }

    // 64-half K-chunks, row pitch 88 halves (176B): 16B-aligned b128 reads,
    // only 2-way LDS bank aliasing (free). Double-buffered for the pipeline.
    __shared__ _Float16 Alds[2][32][88];
    __shared__ _Float16 Blds[2][96][88];

    const v4f vzero = {0.f, 0.f, 0.f, 0.f};
    v4f acc[4];
    acc[0] = vzero; acc[1] = vzero; acc[2] = vzero; acc[3] = vzero;

    if (phase == 0) {
        gemm_loop(24, 8, Alds, Blds,
                  x16 + (size_t)t * B_ * E_, E_, hh_r,
                  Wi0, E_, Wh0,
                  rtile, jtile, tid, acc);
    } else {
        gemm_loop(32, 16, Alds, Blds,
                  hn0 + (size_t)pr * BH, H_, hh_r,
                  Wi1, H_, Wh1,
                  rtile, jtile, tid, acc);
    }

    const int lane = tid & 63, w = tid >> 6;
    const int rh = w & 1, hq = w >> 1;
    const int m = lane & 15, q = lane >> 4;

    // Epilogue. C/D layout: col = lane&15, row = quad*4 + reg.
    const float* bb = bias + phase * 4 * H_;
    float* hf = phase ? h1f : h0f;
    _Float16* hn0w = hn0 + (size_t)pr * BH;   // phase A writes hn0[t&1]
    const int colG = jtile + hq * 16 + m;
    const float br = bb[colG];
    const float bz = bb[H_ + colG];
    const float bi = bb[2 * H_ + colG];
    const float bh = bb[3 * H_ + colG];
#pragma unroll
    for (int reg = 0; reg < 4; ++reg) {
        int rowG = rtile + rh * 16 + q * 4 + reg;
        size_t off = (size_t)rowG * H_ + colG;
        float hprev = hf[off];
        float rr = sigmoidf_(acc[0][reg] + br);
        float zz = sigmoidf_(acc[1][reg] + bz);
        float nn = tanhf_(acc[2][reg] + bi + rr * (acc[3][reg] + bh));
        float hnew = (1.0f - zz) * nn + zz * hprev;
        bool act = rowG < bs_t;
        float hsel = act ? hnew : hprev;
        if (phase == 0) hn0w[off] = (_Float16)hnew;  // layer1 input: unmasked hn
        hh_w[off] = (_Float16)hsel;
        if (act) hf[off] = hnew;
    }
}

// ---------------------------------------------------------------------------
// Preamble / epilogue helpers
// ---------------------------------------------------------------------------
__global__ void cvt_f32_f16(const float* __restrict__ s, _Float16* __restrict__ d, int n) {
    int i = (blockIdx.x * 256 + threadIdx.x) * 8;
    if (i >= n) return;
    float4 v0 = *(const float4*)(s + i);
    float4 v1 = *(const float4*)(s + i + 4);
    v8h o = { (_Float16)v0.x, (_Float16)v0.y, (_Float16)v0.z, (_Float16)v0.w,
              (_Float16)v1.x, (_Float16)v1.y, (_Float16)v1.z, (_Float16)v1.w };
    *(v8h*)(d + i) = o;
}

__global__ void prep_bias(const float* __restrict__ bi0, const float* __restrict__ bh0,
                          const float* __restrict__ bi1, const float* __restrict__ bh1,
                          float* __restrict__ bias) {
    int tid = blockIdx.x * 256 + threadIdx.x;   // 2048 threads
    int l = tid >> 10, j = tid & 1023;
    const float* bi = l ? bi1 : bi0;
    const float* bh = l ? bh1 : bh0;
    float* o = bias + l * 4 * H_;
    o[j]           = bi[j] + bh[j];              // r gate combined
    o[H_ + j]      = bi[H_ + j] + bh[H_ + j];    // z gate combined
    o[2 * H_ + j]  = bi[2 * H_ + j];             // n gate, input part
    o[3 * H_ + j]  = bh[2 * H_ + j];             // n gate, hidden part
}

__global__ void gather_out(const float* __restrict__ h0f, const float* __restrict__ h1f,
                           const int* __restrict__ unsorted, float* __restrict__ out) {
    int rowid = blockIdx.x;          // 256 = L*B
    int l = rowid >> 7, b = rowid & 127;
    int src = unsorted[b];
    const float* s = (l ? h1f : h0f) + (size_t)src * H_;
    float* o = out + (size_t)rowid * H_;
    int c = threadIdx.x * 4;
    *(float4*)(o + c) = *(const float4*)(s + c);
}

// ---------------------------------------------------------------------------
extern "C" void kernel_launch(void* const* d_in, const int* in_sizes, int n_in,
                              void* d_out, int out_size, void* d_ws, size_t ws_size,
                              hipStream_t stream) {
    const float* x    = (const float*)d_in[0];
    const float* Wi0f = (const float*)d_in[1];
    const float* Wh0f = (const float*)d_in[2];
    const float* bi0  = (const float*)d_in[3];
    const float* bh0  = (const float*)d_in[4];
    const float* Wi1f = (const float*)d_in[5];
    const float* Wh1f = (const float*)d_in[6];
    const float* bi1  = (const float*)d_in[7];
    const float* bh1  = (const float*)d_in[8];
    const int*  bs       = (const int*)d_in[9];
    const int*  unsorted = (const int*)d_in[10];
    float* out = (float*)d_out;

    char* ws = (char*)d_ws;
    size_t off = 0;
    auto alloc = [&](size_t bytes) -> char* {
        char* p = ws + off;
        off += (bytes + 255) & ~(size_t)255;
        return p;
    };
    _Float16* x16 = (_Float16*)alloc((size_t)T_ * B_ * E_ * 2);
    _Float16* Wi0 = (_Float16*)alloc((size_t)3 * H_ * E_ * 2);
    _Float16* Wh0 = (_Float16*)alloc((size_t)3 * H_ * H_ * 2);
    _Float16* Wi1 = (_Float16*)alloc((size_t)3 * H_ * H_ * 2);
    _Float16* Wh1 = (_Float16*)alloc((size_t)3 * H_ * H_ * 2);
    float*    bias = (float*)alloc(2 * 4 * H_ * 4);
    char* zbase = ws + off;                  // zero-init block start
    float*    h0f = (float*)alloc((size_t)BH * 4);
    float*    h1f = (float*)alloc((size_t)BH * 4);
    _Float16* h0h = (_Float16*)alloc((size_t)2 * BH * 2);
    _Float16* h1h = (_Float16*)alloc((size_t)2 * BH * 2);
    _Float16* hn0 = (_Float16*)alloc((size_t)2 * BH * 2);
    size_t zbytes = (size_t)((ws + off) - zbase);

    // h states (fp32 masters + fp16 shadows) must start at zero; ws is poisoned.
    hipMemsetAsync(zbase, 0, zbytes, stream);

    cvt_f32_f16<<<(T_ * B_ * E_) / 2048, 256, 0, stream>>>(x, x16, T_ * B_ * E_);
    cvt_f32_f16<<<(3 * H_ * E_) / 2048, 256, 0, stream>>>(Wi0f, Wi0, 3 * H_ * E_);
    cvt_f32_f16<<<(3 * H_ * H_) / 2048, 256, 0, stream>>>(Wh0f, Wh0, 3 * H_ * H_);
    cvt_f32_f16<<<(3 * H_ * H_) / 2048, 256, 0, stream>>>(Wi1f, Wi1, 3 * H_ * H_);
    cvt_f32_f16<<<(3 * H_ * H_) / 2048, 256, 0, stream>>>(Wh1f, Wh1, 3 * H_ * H_);
    prep_bias<<<8, 256, 0, stream>>>(bi0, bh0, bi1, bh1, bias);

    dim3 grid(H_ / 32, B_ / 32, 2);   // 32 hidden-tiles x 4 row-tiles x 2 phases
    for (int k = 0; k <= T_; ++k) {
        gru_step<<<grid, 256, 0, stream>>>(bs, x16, Wi0, Wh0, Wi1, Wh1, bias,
                                           h0f, h1f, h0h, h1h, hn0, k);
    }
    gather_out<<<256, 256, 0, stream>>>(h0f, h1f, unsorted, out);
}

// Round 3
// 10183.491 us; speedup vs baseline: 1.1249x; 1.1249x over previous
//
#include <hip/hip_runtime.h>
#include <cstdint>
#include <cstddef>

#define T_ 256
#define B_ 128
#define E_ 512
#define H_ 1024
#define BH (B_*H_)
#define NWG 256   // 32 jtiles x 4 rtiles x 2 phases — one WG per CU, persistent

typedef _Float16 v8h __attribute__((ext_vector_type(8)));
typedef float    v4f __attribute__((ext_vector_type(4)));
typedef unsigned int u32x4 __attribute__((ext_vector_type(4)));

__device__ __forceinline__ float sigmoidf_(float x) {
    return 1.0f / (1.0f + __expf(-x));
}
__device__ __forceinline__ float tanhf_(float x) {
    // tanh(x) = 1 - 2/(exp(2x)+1); saturates correctly at +/-inf
    return 1.0f - 2.0f / (__expf(2.0f * x) + 1.0f);
}

// --- agent-coherent (cross-XCD) accessors: bypass L1/L2 so readers on other
// XCDs always see fresh data without any cache-invalidate at the barrier
// (a buffer_inv would evict the L2-warm weights — the whole point is to
// keep them resident). Only the mutable h-state uses these.
// NOTE: asm operands must be ext_vector types, not HIP's uint4 struct
// (clang: "indirect register inputs" otherwise).
__device__ __forceinline__ u32x4 sc_load16(const void* p) {
    u32x4 v;
    asm volatile("global_load_dwordx4 %0, %1, off sc0 sc1"
                 : "=v"(v) : "v"(p) : "memory");
    return v;
}
__device__ __forceinline__ void sc_store16(void* p, u32x4 v) {
    asm volatile("global_store_dwordx4 %0, %1, off sc0 sc1"
                 :: "v"(p), "v"(v) : "memory");
}
__device__ __forceinline__ void sc_store2(void* p, unsigned v) {
    asm volatile("global_store_short %0, %1, off sc0 sc1"
                 :: "v"(p), "v"(v) : "memory");
}
#define VMCNT0() asm volatile("s_waitcnt vmcnt(0)" ::: "memory")

// ---------------------------------------------------------------------------
// Persistent fused GRU kernel. One launch; loop k=0..T with a hand-rolled
// grid barrier between iterations. Iteration k runs:
//   phase A (blockIdx.z==0): layer0 at t=k      (skipped when k==T)
//   phase B (blockIdx.z==1): layer1 at t=k-1    (skipped when k==0)
// Each WG keeps the same (phase, rtile, jtile) for the whole run, so its
// weight slice stays warm in its XCD's L2 across all 256 timesteps.
// fp16 h-shadows and hn0 ping-pong on (t&1); they cross WGs/XCDs so all
// accesses to them are sc0sc1 (agent-coherent). fp32 h masters are
// WG-private (same persistent WG reads & writes its own tile) -> cached.
// WG = 32 rows x 32 hidden units (96 gate columns), 4 waves.
// ---------------------------------------------------------------------------
__global__ __launch_bounds__(256) void gru_persist(
    const int* __restrict__ bs,
    const _Float16* __restrict__ x16,   // [T][B][E]
    const _Float16* __restrict__ Wi0,   // [3072][512]
    const _Float16* __restrict__ Wh0,   // [3072][1024]
    const _Float16* __restrict__ Wi1,   // [3072][1024]
    const _Float16* __restrict__ Wh1,   // [3072][1024]
    const float* __restrict__ bias,     // [2][4][1024] : br,bz,b_in,b_hn
    float* __restrict__ h0f, float* __restrict__ h1f,       // fp32 masters
    _Float16* __restrict__ h0h, _Float16* __restrict__ h1h, // fp16 shadow x2
    _Float16* __restrict__ hn0,                             // layer0 out x2
    int* __restrict__ barctr)
{
    const int phase = blockIdx.z;
    const int rtile = blockIdx.y * 32;
    const int jtile = blockIdx.x * 32;
    const int tid = threadIdx.x;

    const int lane = tid & 63, w = tid >> 6;
    const int rh = w & 1, hq = w >> 1;
    const int m = lane & 15, q = lane >> 4;

    // 64-half K-chunks, row pitch 88 halves (176B): 16B-aligned b128 reads,
    // only 2-way LDS bank aliasing (free).
    __shared__ _Float16 Alds[32][88];
    __shared__ _Float16 Blds[96][88];

    // loop-invariant epilogue constants
    const float* bb = bias + phase * 4 * H_;
    float* hf = phase ? h1f : h0f;
    _Float16* hh = phase ? h1h : h0h;
    const int colG = jtile + hq * 16 + m;
    const float br = bb[colG];
    const float bz = bb[H_ + colG];
    const float bi = bb[2 * H_ + colG];
    const float bh = bb[3 * H_ + colG];

    for (int k = 0; k <= T_; ++k) {
        const bool active = !((phase == 0 && k >= T_) || (phase == 1 && k == 0));
        if (active) {
            const int t = phase ? (k - 1) : k;
            const int bs_t = bs[t];
            const int pr = t & 1, pw = (t + 1) & 1;
            const _Float16* hh_r = hh + (size_t)pr * BH;
            _Float16*       hh_w = hh + (size_t)pw * BH;

            if (rtile >= bs_t) {
                // Inactive tile: keep the ping-pong coherent (agent-scope).
                if (tid < 128) {
                    int r = tid >> 2, cc = tid & 3;
                    size_t off = (size_t)(rtile + r) * H_ + jtile + cc * 8;
                    u32x4 v = sc_load16(hh_r + off);
                    VMCNT0();
                    sc_store16(hh_w + off, v);
                }
            } else {
                const _Float16 *aseg0, *aseg1, *bseg0, *bseg1;
                int apitch0, nch, k0ch;
                if (phase == 0) {
                    aseg0 = x16 + (size_t)t * B_ * E_;  apitch0 = E_;
                    aseg1 = hh_r;
                    bseg0 = Wi0;
                    bseg1 = Wh0;
                    nch = 24; k0ch = 8;        // 512/64 + 1024/64
                } else {
                    aseg0 = hn0 + (size_t)pr * BH;  apitch0 = H_;
                    aseg1 = hh_r;
                    bseg0 = Wi1;
                    bseg1 = Wh1;
                    nch = 32; k0ch = 16;       // 1024/64 + 1024/64
                }

                const v4f vzero = {0.f, 0.f, 0.f, 0.f};
                v4f acc[4];
                acc[0] = vzero; acc[1] = vzero; acc[2] = vzero; acc[3] = vzero;

                for (int kc = 0; kc < nch; ++kc) {
                    const int seg = (kc >= k0ch);
                    const int koff = (seg ? (kc - k0ch) : kc) * 64;
                    const _Float16* as   = seg ? aseg1 : aseg0;
                    const int       ap   = seg ? H_ : apitch0;
                    const _Float16* bsrc = seg ? bseg1 : bseg0;
                    const int       bp   = (phase == 0 && !seg) ? E_ : H_;
                    // h / hn0 sources cross XCDs -> agent-coherent loads;
                    // x16 (phase A seg0) is read-only -> normal cached.
                    const bool a_sc = (phase == 1) || seg;

                    __syncthreads();
                    // weights: normal cached loads (L2-warm after step 0)
                    u32x4 bv[3];
#pragma unroll
                    for (int i = 0; i < 3; ++i) {
                        int id = tid + i * 256;
                        int cl = id >> 3, cc = id & 7, g = cl >> 5, j = cl & 31;
                        bv[i] = *(const u32x4*)(bsrc + (size_t)(g * H_ + jtile + j) * bp + koff + cc * 8);
                    }
                    int row = tid >> 3, cc2 = tid & 7;
                    const _Float16* aptr = as + (size_t)(rtile + row) * ap + koff + cc2 * 8;
                    u32x4 av;
                    if (a_sc) { av = sc_load16(aptr); VMCNT0(); }
                    else      { av = *(const u32x4*)aptr; }
                    *(u32x4*)&Alds[row][cc2 * 8] = av;
#pragma unroll
                    for (int i = 0; i < 3; ++i) {
                        int id = tid + i * 256;
                        *(u32x4*)&Blds[id >> 3][(id & 7) * 8] = bv[i];
                    }
                    __syncthreads();

#pragma unroll
                    for (int s = 0; s < 2; ++s) {
                        v8h a  = *(const v8h*)&Alds[rh * 16 + m][s * 32 + q * 8];
                        v8h b0 = *(const v8h*)&Blds[ 0 + hq * 16 + m][s * 32 + q * 8];
                        v8h b1 = *(const v8h*)&Blds[32 + hq * 16 + m][s * 32 + q * 8];
                        v8h b2 = *(const v8h*)&Blds[64 + hq * 16 + m][s * 32 + q * 8];
                        acc[0] = __builtin_amdgcn_mfma_f32_16x16x32_f16(a, b0, acc[0], 0, 0, 0);
                        acc[1] = __builtin_amdgcn_mfma_f32_16x16x32_f16(a, b1, acc[1], 0, 0, 0);
                        if (seg) acc[3] = __builtin_amdgcn_mfma_f32_16x16x32_f16(a, b2, acc[3], 0, 0, 0);
                        else     acc[2] = __builtin_amdgcn_mfma_f32_16x16x32_f16(a, b2, acc[2], 0, 0, 0);
                    }
                }

                // Epilogue. C/D layout: col = lane&15, row = quad*4 + reg.
                _Float16* hn0w = hn0 + (size_t)pr * BH;   // phase A writes hn0[t&1]
#pragma unroll
                for (int reg = 0; reg < 4; ++reg) {
                    int rowG = rtile + rh * 16 + q * 4 + reg;
                    size_t off = (size_t)rowG * H_ + colG;
                    float hprev = hf[off];
                    float rr = sigmoidf_(acc[0][reg] + br);
                    float zz = sigmoidf_(acc[1][reg] + bz);
                    float nn = tanhf_(acc[2][reg] + bi + rr * (acc[3][reg] + bh));
                    float hnew = (1.0f - zz) * nn + zz * hprev;
                    bool act = rowG < bs_t;
                    float hsel = act ? hnew : hprev;
                    if (phase == 0)   // layer1 input: unmasked hn
                        sc_store2(hn0w + off, (unsigned)__builtin_bit_cast(unsigned short, (_Float16)hnew));
                    sc_store2(hh_w + off, (unsigned)__builtin_bit_cast(unsigned short, (_Float16)hsel));
                    if (act) hf[off] = hnew;   // WG-private fp32 master: cached
                }
            }
        }

        // ---- grid barrier (no L2 invalidate: weights stay warm) ----
        if (k < T_) {
            VMCNT0();            // each wave drains its own sc-stores
            __syncthreads();     // whole WG done
            if (tid == 0) {
                __hip_atomic_fetch_add(barctr, 1, __ATOMIC_RELEASE, __HIP_MEMORY_SCOPE_AGENT);
                const int target = NWG * (k + 1);
                while (__hip_atomic_load(barctr, __ATOMIC_RELAXED, __HIP_MEMORY_SCOPE_AGENT) < target) {
                    __builtin_amdgcn_s_sleep(4);
                }
            }
            __syncthreads();
        }
    }
}

// ---------------------------------------------------------------------------
// Preamble / epilogue helpers
// ---------------------------------------------------------------------------
__global__ void cvt_f32_f16(const float* __restrict__ s, _Float16* __restrict__ d, int n) {
    int i = (blockIdx.x * 256 + threadIdx.x) * 8;
    if (i >= n) return;
    float4 v0 = *(const float4*)(s + i);
    float4 v1 = *(const float4*)(s + i + 4);
    v8h o = { (_Float16)v0.x, (_Float16)v0.y, (_Float16)v0.z, (_Float16)v0.w,
              (_Float16)v1.x, (_Float16)v1.y, (_Float16)v1.z, (_Float16)v1.w };
    *(v8h*)(d + i) = o;
}

__global__ void prep_bias(const float* __restrict__ bi0, const float* __restrict__ bh0,
                          const float* __restrict__ bi1, const float* __restrict__ bh1,
                          float* __restrict__ bias) {
    int tid = blockIdx.x * 256 + threadIdx.x;   // 2048 threads
    int l = tid >> 10, j = tid & 1023;
    const float* bi = l ? bi1 : bi0;
    const float* bh = l ? bh1 : bh0;
    float* o = bias + l * 4 * H_;
    o[j]           = bi[j] + bh[j];              // r gate combined
    o[H_ + j]      = bi[H_ + j] + bh[H_ + j];    // z gate combined
    o[2 * H_ + j]  = bi[2 * H_ + j];             // n gate, input part
    o[3 * H_ + j]  = bh[2 * H_ + j];             // n gate, hidden part
}

__global__ void gather_out(const float* __restrict__ h0f, const float* __restrict__ h1f,
                           const int* __restrict__ unsorted, float* __restrict__ out) {
    int rowid = blockIdx.x;          // 256 = L*B
    int l = rowid >> 7, b = rowid & 127;
    int src = unsorted[b];
    const float* s = (l ? h1f : h0f) + (size_t)src * H_;
    float* o = out + (size_t)rowid * H_;
    int c = threadIdx.x * 4;
    *(float4*)(o + c) = *(const float4*)(s + c);
}

// ---------------------------------------------------------------------------
extern "C" void kernel_launch(void* const* d_in, const int* in_sizes, int n_in,
                              void* d_out, int out_size, void* d_ws, size_t ws_size,
                              hipStream_t stream) {
    const float* x    = (const float*)d_in[0];
    const float* Wi0f = (const float*)d_in[1];
    const float* Wh0f = (const float*)d_in[2];
    const float* bi0  = (const float*)d_in[3];
    const float* bh0  = (const float*)d_in[4];
    const float* Wi1f = (const float*)d_in[5];
    const float* Wh1f = (const float*)d_in[6];
    const float* bi1  = (const float*)d_in[7];
    const float* bh1  = (const float*)d_in[8];
    const int*  bs       = (const int*)d_in[9];
    const int*  unsorted = (const int*)d_in[10];
    float* out = (float*)d_out;

    char* ws = (char*)d_ws;
    size_t off = 0;
    auto alloc = [&](size_t bytes) -> char* {
        char* p = ws + off;
        off += (bytes + 255) & ~(size_t)255;
        return p;
    };
    _Float16* x16 = (_Float16*)alloc((size_t)T_ * B_ * E_ * 2);
    _Float16* Wi0 = (_Float16*)alloc((size_t)3 * H_ * E_ * 2);
    _Float16* Wh0 = (_Float16*)alloc((size_t)3 * H_ * H_ * 2);
    _Float16* Wi1 = (_Float16*)alloc((size_t)3 * H_ * H_ * 2);
    _Float16* Wh1 = (_Float16*)alloc((size_t)3 * H_ * H_ * 2);
    float*    bias = (float*)alloc(2 * 4 * H_ * 4);
    char* zbase = ws + off;                  // zero-init block start
    float*    h0f = (float*)alloc((size_t)BH * 4);
    float*    h1f = (float*)alloc((size_t)BH * 4);
    _Float16* h0h = (_Float16*)alloc((size_t)2 * BH * 2);
    _Float16* h1h = (_Float16*)alloc((size_t)2 * BH * 2);
    _Float16* hn0 = (_Float16*)alloc((size_t)2 * BH * 2);
    int*      barctr = (int*)alloc(256);
    size_t zbytes = (size_t)((ws + off) - zbase);

    // h states (fp32 masters + fp16 shadows) + barrier counter start at zero.
    (void)hipMemsetAsync(zbase, 0, zbytes, stream);

    cvt_f32_f16<<<(T_ * B_ * E_) / 2048, 256, 0, stream>>>(x, x16, T_ * B_ * E_);
    cvt_f32_f16<<<(3 * H_ * E_) / 2048, 256, 0, stream>>>(Wi0f, Wi0, 3 * H_ * E_);
    cvt_f32_f16<<<(3 * H_ * H_) / 2048, 256, 0, stream>>>(Wh0f, Wh0, 3 * H_ * H_);
    cvt_f32_f16<<<(3 * H_ * H_) / 2048, 256, 0, stream>>>(Wi1f, Wi1, 3 * H_ * H_);
    cvt_f32_f16<<<(3 * H_ * H_) / 2048, 256, 0, stream>>>(Wh1f, Wh1, 3 * H_ * H_);
    prep_bias<<<8, 256, 0, stream>>>(bi0, bh0, bi1, bh1, bias);

    // Persistent kernel: 256 WGs on 256 CUs (22.5 KiB LDS, 256 thr -> all
    // co-resident; spin barrier is safe).
    dim3 grid(H_ / 32, B_ / 32, 2);
    gru_persist<<<grid, 256, 0, stream>>>(bs, x16, Wi0, Wh0, Wi1, Wh1, bias,
                                          h0f, h1f, h0h, h1h, hn0, barctr);
    gather_out<<<256, 256, 0, stream>>>(h0f, h1f, unsorted, out);
}

// Round 4
// 7494.867 us; speedup vs baseline: 1.5284x; 1.3587x over previous
//
#include <hip/hip_runtime.h>
#include <cstdint>
#include <cstddef>

#define T_ 256
#define B_ 128
#define E_ 512
#define H_ 1024
#define BH (B_*H_)
#define NWG 256   // 32 jtiles x 4 rtiles x 2 phases — one WG per CU, persistent
#define PP 2056   // panel pitch in halves: 2048 + 8 pad -> row stride 4112B (2-way bank alias only)

typedef _Float16 v8h __attribute__((ext_vector_type(8)));
typedef float    v4f __attribute__((ext_vector_type(4)));
typedef unsigned int u32x4 __attribute__((ext_vector_type(4)));

__device__ __forceinline__ float sigmoidf_(float x) {
    return 1.0f / (1.0f + __expf(-x));
}
__device__ __forceinline__ float tanhf_(float x) {
    // tanh(x) = 1 - 2/(exp(2x)+1); saturates correctly at +/-inf
    return 1.0f - 2.0f / (__expf(2.0f * x) + 1.0f);
}

// --- agent-coherent (cross-XCD) accessors: bypass L1/L2 so readers on other
// XCDs always see fresh data without any cache-invalidate at the barrier
// (a buffer_inv would evict the L2-warm weights — the whole point is to
// keep them resident). Only the mutable h-state uses these.
__device__ __forceinline__ u32x4 sc_load16(const void* p) {
    u32x4 v;
    asm volatile("global_load_dwordx4 %0, %1, off sc0 sc1"
                 : "=v"(v) : "v"(p) : "memory");
    return v;
}
__device__ __forceinline__ void sc_store16(void* p, u32x4 v) {
    asm volatile("global_store_dwordx4 %0, %1, off sc0 sc1"
                 :: "v"(p), "v"(v) : "memory");
}
__device__ __forceinline__ void sc_store2(void* p, unsigned v) {
    asm volatile("global_store_short %0, %1, off sc0 sc1"
                 :: "v"(p), "v"(v) : "memory");
}
#define VMCNT0() asm volatile("s_waitcnt vmcnt(0)" ::: "memory")

// ---------------------------------------------------------------------------
// Persistent fused GRU kernel, R4: per-iteration A-PANEL prefetch into LDS
// (amortizes the uncached cross-XCD load latency 32x -> ~4x per iteration)
// + sharded grid barrier (8 arrival lines + read-only epoch word).
//   iteration k: phase A (z==0): layer0 t=k; phase B (z==1): layer1 t=k-1.
// Weights stay L2-warm on each WG's XCD for all 256 steps (normal cached
// loads, never invalidated). Mutable h-state crosses XCDs via sc0sc1.
// WG = 32 rows x 32 hidden units (96 gate columns), 4 waves, 1 WG/CU.
// ---------------------------------------------------------------------------
__global__ __launch_bounds__(256) void gru_persist(
    const int* __restrict__ bs,
    const _Float16* __restrict__ x16,   // [T][B][E]
    const _Float16* __restrict__ Wi0,   // [3072][512]
    const _Float16* __restrict__ Wh0,   // [3072][1024]
    const _Float16* __restrict__ Wi1,   // [3072][1024]
    const _Float16* __restrict__ Wh1,   // [3072][1024]
    const float* __restrict__ bias,     // [2][4][1024] : br,bz,b_in,b_hn
    float* __restrict__ h0f, float* __restrict__ h1f,       // fp32 masters
    _Float16* __restrict__ h0h, _Float16* __restrict__ h1h, // fp16 shadow x2
    _Float16* __restrict__ hn0,                             // layer0 out x2
    int* __restrict__ barctr)
{
    const int phase = blockIdx.z;
    const int rtile = blockIdx.y * 32;
    const int jtile = blockIdx.x * 32;
    const int tid = threadIdx.x;

    const int lane = tid & 63, w = tid >> 6;
    const int rh = w & 1, hq = w >> 1;
    const int m = lane & 15, q = lane >> 4;

    // A-panel: one WG-row-block of [x|h] (phase A: 512+1024 cols) or
    // [hn0|h] (phase B: 1024+1024 cols), refreshed once per iteration.
    __shared__ _Float16 Pan[32][PP];        // 131,584 B
    // Weight staging: 96 gate cols x 64 halves, pitch 88 (2-way alias only).
    __shared__ _Float16 Blds[96][88];       //  16,896 B  (total 148,480 B)

    // loop-invariant epilogue constants
    const float* bb = bias + phase * 4 * H_;
    float* hf = phase ? h1f : h0f;
    _Float16* hh = phase ? h1h : h0h;
    const int colG = jtile + hq * 16 + m;
    const float br = bb[colG];
    const float bz = bb[H_ + colG];
    const float bi = bb[2 * H_ + colG];
    const float bh = bb[3 * H_ + colG];

    // barrier shards: 8 arrival lines (256B apart), master, epoch word
    const int wgid = ((int)blockIdx.z * 4 + (int)blockIdx.y) * 32 + (int)blockIdx.x;
    int* shard  = barctr + (wgid & 7) * 64;
    int* master = barctr + 8 * 64;
    int* epoch  = barctr + 9 * 64;

    // panel prefetch mapping: 8 threads per row, 16B units
    const int prow = tid >> 3, pslot = tid & 7;

    for (int k = 0; k <= T_; ++k) {
        const bool active = !((phase == 0 && k >= T_) || (phase == 1 && k == 0));
        if (active) {
            const int t = phase ? (k - 1) : k;
            const int bs_t = bs[t];
            const int pr = t & 1, pw = (t + 1) & 1;
            const _Float16* hh_r = hh + (size_t)pr * BH;
            _Float16*       hh_w = hh + (size_t)pw * BH;

            if (rtile >= bs_t) {
                // Inactive tile: keep the ping-pong coherent (agent-scope).
                if (tid < 128) {
                    int r = tid >> 2, cc = tid & 3;
                    size_t off = (size_t)(rtile + r) * H_ + jtile + cc * 8;
                    u32x4 v = sc_load16(hh_r + off);
                    VMCNT0();
                    sc_store16(hh_w + off, v);
                }
            } else {
                const _Float16 *bseg0, *bseg1, *ps0, *ps1;
                int nch, k0ch, nu0, nj;
                bool s0_sc;
                if (phase == 0) {
                    bseg0 = Wi0; bseg1 = Wh0;
                    nch = 24; k0ch = 8;        // 512/64 + 1024/64
                    ps0 = x16 + (size_t)t * B_ * E_ + (size_t)(rtile + prow) * E_;
                    ps1 = hh_r + (size_t)(rtile + prow) * H_;
                    nu0 = 64;  nj = 24;  s0_sc = false;   // x: read-only, cached
                } else {
                    bseg0 = Wi1; bseg1 = Wh1;
                    nch = 32; k0ch = 16;       // 1024/64 + 1024/64
                    ps0 = hn0 + (size_t)pr * BH + (size_t)(rtile + prow) * H_;
                    ps1 = hh_r + (size_t)(rtile + prow) * H_;
                    nu0 = 128; nj = 32;  s0_sc = true;
                }

                // ---- panel prefetch: batched issue -> single drain -> LDS ----
                for (int jb = 0; jb < nj; jb += 8) {
                    u32x4 v[8];
#pragma unroll
                    for (int j = 0; j < 8; ++j) {
                        int u = pslot + (jb + j) * 8;
                        const _Float16* p = (u < nu0) ? (ps0 + u * 8)
                                                      : (ps1 + (u - nu0) * 8);
                        bool use_sc = s0_sc || (u >= nu0);
                        if (use_sc) v[j] = sc_load16(p);
                        else        v[j] = *(const u32x4*)p;
                    }
                    VMCNT0();
#pragma unroll
                    for (int j = 0; j < 8; ++j) {
                        int u = pslot + (jb + j) * 8;
                        *(u32x4*)&Pan[prow][u * 8] = v[j];
                    }
                }

                const v4f vzero = {0.f, 0.f, 0.f, 0.f};
                v4f acc[4];
                acc[0] = vzero; acc[1] = vzero; acc[2] = vzero; acc[3] = vzero;

                for (int kc = 0; kc < nch; ++kc) {
                    const int seg = (kc >= k0ch);
                    const int koff = (seg ? (kc - k0ch) : kc) * 64;
                    const _Float16* bsrc = seg ? bseg1 : bseg0;
                    const int       bp   = (phase == 0 && !seg) ? E_ : H_;

                    __syncthreads();   // Blds reuse (+ panel ready on kc==0)
                    // weights: normal cached loads (L2-warm after step 0)
                    u32x4 bv[3];
#pragma unroll
                    for (int i = 0; i < 3; ++i) {
                        int id = tid + i * 256;
                        int cl = id >> 3, cc = id & 7, g = cl >> 5, j = cl & 31;
                        bv[i] = *(const u32x4*)(bsrc + (size_t)(g * H_ + jtile + j) * bp + koff + cc * 8);
                    }
#pragma unroll
                    for (int i = 0; i < 3; ++i) {
                        int id = tid + i * 256;
                        *(u32x4*)&Blds[id >> 3][(id & 7) * 8] = bv[i];
                    }
                    __syncthreads();

#pragma unroll
                    for (int s = 0; s < 2; ++s) {
                        v8h a  = *(const v8h*)&Pan[rh * 16 + m][kc * 64 + s * 32 + q * 8];
                        v8h b0 = *(const v8h*)&Blds[ 0 + hq * 16 + m][s * 32 + q * 8];
                        v8h b1 = *(const v8h*)&Blds[32 + hq * 16 + m][s * 32 + q * 8];
                        v8h b2 = *(const v8h*)&Blds[64 + hq * 16 + m][s * 32 + q * 8];
                        acc[0] = __builtin_amdgcn_mfma_f32_16x16x32_f16(a, b0, acc[0], 0, 0, 0);
                        acc[1] = __builtin_amdgcn_mfma_f32_16x16x32_f16(a, b1, acc[1], 0, 0, 0);
                        if (seg) acc[3] = __builtin_amdgcn_mfma_f32_16x16x32_f16(a, b2, acc[3], 0, 0, 0);
                        else     acc[2] = __builtin_amdgcn_mfma_f32_16x16x32_f16(a, b2, acc[2], 0, 0, 0);
                    }
                }

                // Epilogue. C/D layout: col = lane&15, row = quad*4 + reg.
                _Float16* hn0w = hn0 + (size_t)pr * BH;   // phase A writes hn0[t&1]
#pragma unroll
                for (int reg = 0; reg < 4; ++reg) {
                    int rowG = rtile + rh * 16 + q * 4 + reg;
                    size_t off = (size_t)rowG * H_ + colG;
                    float hprev = hf[off];
                    float rr = sigmoidf_(acc[0][reg] + br);
                    float zz = sigmoidf_(acc[1][reg] + bz);
                    float nn = tanhf_(acc[2][reg] + bi + rr * (acc[3][reg] + bh));
                    float hnew = (1.0f - zz) * nn + zz * hprev;
                    bool act = rowG < bs_t;
                    float hsel = act ? hnew : hprev;
                    if (phase == 0)   // layer1 input: unmasked hn
                        sc_store2(hn0w + off, (unsigned)__builtin_bit_cast(unsigned short, (_Float16)hnew));
                    sc_store2(hh_w + off, (unsigned)__builtin_bit_cast(unsigned short, (_Float16)hsel));
                    if (act) hf[off] = hnew;   // WG-private fp32 master: cached
                }
            }
        }

        // ---- sharded grid barrier (no L2 invalidate: weights stay warm) ----
        if (k < T_) {
            VMCNT0();            // each wave drains its own sc-stores
            __syncthreads();     // whole WG done (=> all waves drained)
            if (tid == 0) {
                // arrivals sharded over 8 lines: 32 serialized RMWs max
                int old = __hip_atomic_fetch_add(shard, 1, __ATOMIC_RELAXED, __HIP_MEMORY_SCOPE_AGENT);
                if (old + 1 == 32 * (k + 1)) {
                    int mo = __hip_atomic_fetch_add(master, 1, __ATOMIC_RELAXED, __HIP_MEMORY_SCOPE_AGENT);
                    if (mo + 1 == 8 * (k + 1)) {
                        __hip_atomic_store(epoch, k + 1, __ATOMIC_RELEASE, __HIP_MEMORY_SCOPE_AGENT);
                    }
                }
                // read-only polling of one line: no RMW contention
                while (__hip_atomic_load(epoch, __ATOMIC_RELAXED, __HIP_MEMORY_SCOPE_AGENT) < k + 1) {
                    __builtin_amdgcn_s_sleep(8);
                }
            }
            __syncthreads();
        }
    }
}

// ---------------------------------------------------------------------------
// Preamble / epilogue helpers
// ---------------------------------------------------------------------------
__global__ void cvt_f32_f16(const float* __restrict__ s, _Float16* __restrict__ d, int n) {
    int i = (blockIdx.x * 256 + threadIdx.x) * 8;
    if (i >= n) return;
    float4 v0 = *(const float4*)(s + i);
    float4 v1 = *(const float4*)(s + i + 4);
    v8h o = { (_Float16)v0.x, (_Float16)v0.y, (_Float16)v0.z, (_Float16)v0.w,
              (_Float16)v1.x, (_Float16)v1.y, (_Float16)v1.z, (_Float16)v1.w };
    *(v8h*)(d + i) = o;
}

__global__ void prep_bias(const float* __restrict__ bi0, const float* __restrict__ bh0,
                          const float* __restrict__ bi1, const float* __restrict__ bh1,
                          float* __restrict__ bias) {
    int tid = blockIdx.x * 256 + threadIdx.x;   // 2048 threads
    int l = tid >> 10, j = tid & 1023;
    const float* bi = l ? bi1 : bi0;
    const float* bh = l ? bh1 : bh0;
    float* o = bias + l * 4 * H_;
    o[j]           = bi[j] + bh[j];              // r gate combined
    o[H_ + j]      = bi[H_ + j] + bh[H_ + j];    // z gate combined
    o[2 * H_ + j]  = bi[2 * H_ + j];             // n gate, input part
    o[3 * H_ + j]  = bh[2 * H_ + j];             // n gate, hidden part
}

__global__ void gather_out(const float* __restrict__ h0f, const float* __restrict__ h1f,
                           const int* __restrict__ unsorted, float* __restrict__ out) {
    int rowid = blockIdx.x;          // 256 = L*B
    int l = rowid >> 7, b = rowid & 127;
    int src = unsorted[b];
    const float* s = (l ? h1f : h0f) + (size_t)src * H_;
    float* o = out + (size_t)rowid * H_;
    int c = threadIdx.x * 4;
    *(float4*)(o + c) = *(const float4*)(s + c);
}

// ---------------------------------------------------------------------------
extern "C" void kernel_launch(void* const* d_in, const int* in_sizes, int n_in,
                              void* d_out, int out_size, void* d_ws, size_t ws_size,
                              hipStream_t stream) {
    const float* x    = (const float*)d_in[0];
    const float* Wi0f = (const float*)d_in[1];
    const float* Wh0f = (const float*)d_in[2];
    const float* bi0  = (const float*)d_in[3];
    const float* bh0  = (const float*)d_in[4];
    const float* Wi1f = (const float*)d_in[5];
    const float* Wh1f = (const float*)d_in[6];
    const float* bi1  = (const float*)d_in[7];
    const float* bh1  = (const float*)d_in[8];
    const int*  bs       = (const int*)d_in[9];
    const int*  unsorted = (const int*)d_in[10];
    float* out = (float*)d_out;

    char* ws = (char*)d_ws;
    size_t off = 0;
    auto alloc = [&](size_t bytes) -> char* {
        char* p = ws + off;
        off += (bytes + 255) & ~(size_t)255;
        return p;
    };
    _Float16* x16 = (_Float16*)alloc((size_t)T_ * B_ * E_ * 2);
    _Float16* Wi0 = (_Float16*)alloc((size_t)3 * H_ * E_ * 2);
    _Float16* Wh0 = (_Float16*)alloc((size_t)3 * H_ * H_ * 2);
    _Float16* Wi1 = (_Float16*)alloc((size_t)3 * H_ * H_ * 2);
    _Float16* Wh1 = (_Float16*)alloc((size_t)3 * H_ * H_ * 2);
    float*    bias = (float*)alloc(2 * 4 * H_ * 4);
    char* zbase = ws + off;                  // zero-init block start
    float*    h0f = (float*)alloc((size_t)BH * 4);
    float*    h1f = (float*)alloc((size_t)BH * 4);
    _Float16* h0h = (_Float16*)alloc((size_t)2 * BH * 2);
    _Float16* h1h = (_Float16*)alloc((size_t)2 * BH * 2);
    _Float16* hn0 = (_Float16*)alloc((size_t)2 * BH * 2);
    int*      barctr = (int*)alloc(4096);    // 8 shards + master + epoch, 256B apart
    size_t zbytes = (size_t)((ws + off) - zbase);

    // h states (fp32 masters + fp16 shadows) + barrier block start at zero.
    (void)hipMemsetAsync(zbase, 0, zbytes, stream);

    cvt_f32_f16<<<(T_ * B_ * E_) / 2048, 256, 0, stream>>>(x, x16, T_ * B_ * E_);
    cvt_f32_f16<<<(3 * H_ * E_) / 2048, 256, 0, stream>>>(Wi0f, Wi0, 3 * H_ * E_);
    cvt_f32_f16<<<(3 * H_ * H_) / 2048, 256, 0, stream>>>(Wh0f, Wh0, 3 * H_ * H_);
    cvt_f32_f16<<<(3 * H_ * H_) / 2048, 256, 0, stream>>>(Wi1f, Wi1, 3 * H_ * H_);
    cvt_f32_f16<<<(3 * H_ * H_) / 2048, 256, 0, stream>>>(Wh1f, Wh1, 3 * H_ * H_);
    prep_bias<<<8, 256, 0, stream>>>(bi0, bh0, bi1, bh1, bias);

    // Persistent kernel: 256 WGs on 256 CUs (148.5 KiB LDS -> exactly 1 WG/CU,
    // all co-resident; spin barrier is safe).
    dim3 grid(H_ / 32, B_ / 32, 2);
    gru_persist<<<grid, 256, 0, stream>>>(bs, x16, Wi0, Wh0, Wi1, Wh1, bias,
                                          h0f, h1f, h0h, h1h, hn0, barctr);
    gather_out<<<256, 256, 0, stream>>>(h0f, h1f, unsorted, out);
}